// Round 12
// baseline (404.781 us; speedup 1.0000x reference)
//
#include <hip/hip_runtime.h>

typedef __attribute__((ext_vector_type(8))) short bf16x8;
typedef __attribute__((ext_vector_type(8))) unsigned short ushort8;
typedef __attribute__((ext_vector_type(4))) unsigned short ushort4v;
typedef __attribute__((ext_vector_type(4))) float f32x4;
typedef __attribute__((ext_vector_type(4))) float float4v;
typedef __attribute__((ext_vector_type(8))) _Float16 f16x8;

__device__ inline unsigned short f2bf(float f){
  unsigned u = __builtin_bit_cast(unsigned, f);
  return (unsigned short)((u + 0x7fffu + ((u>>16)&1u)) >> 16);
}
__device__ inline float bf2f(unsigned short h){
  return __builtin_bit_cast(float, (unsigned)h << 16);
}
__device__ inline unsigned short f2h(float f){
  return __builtin_bit_cast(unsigned short, (_Float16)f);
}
__device__ inline float h2f(unsigned short u){
  return (float)__builtin_bit_cast(_Float16, u);
}

__device__ inline void gll16(const void* g, void* l){
  __builtin_amdgcn_global_load_lds((const __attribute__((address_space(1))) void*)g,
                                   (__attribute__((address_space(3))) void*)l, 16, 0, 0);
}

// ---------------- LayerNorm: one wave per row -> XN [65536][256] bf16 (dense)
__global__ __launch_bounds__(256) void k_ln(const float* __restrict__ x,
                                            const float* __restrict__ g,
                                            unsigned short* __restrict__ XN){
  int wid = threadIdx.x >> 6, lane = threadIdx.x & 63;
  int row = blockIdx.x*4 + wid;
  float4v v = *(const float4v*)&x[(size_t)row*256 + lane*4];
  float4v gv = *(const float4v*)&g[lane*4];
  float s  = v[0]+v[1]+v[2]+v[3];
  float s2 = v[0]*v[0]+v[1]*v[1]+v[2]*v[2]+v[3]*v[3];
  #pragma unroll
  for (int m=32; m>=1; m>>=1){ s += __shfl_xor(s, m, 64); s2 += __shfl_xor(s2, m, 64); }
  float mu  = s*(1.f/256.f);
  float var = s2*(1.f/256.f) - mu*mu;
  float rst = rsqrtf(var + 1e-6f);
  ushort4v o;
  #pragma unroll
  for (int e=0;e<4;e++) o[e] = f2bf((v[e]-mu)*rst*gv[e]);
  *(ushort4v*)&XN[(size_t)row*256 + lane*4] = o;
}

// ---------------- column partial sums (dense XN), coalesced
__global__ __launch_bounds__(256) void k_cm1(const unsigned short* __restrict__ XN,
                                             float* __restrict__ psum){
  __shared__ float red[8][256];
  int blk = blockIdx.x, t = threadIdx.x;
  int rs = t >> 5, c8 = (t & 31)*8;
  float a[8] = {0,0,0,0,0,0,0,0};
  #pragma unroll
  for (int i=0; i<8; ++i){
    int row = blk*64 + rs + i*8;
    ushort8 v = *(const ushort8*)&XN[(size_t)row*256 + c8];
    #pragma unroll
    for (int e=0;e<8;e++) a[e] += bf2f(v[e]);
  }
  #pragma unroll
  for (int e=0;e<8;e++) red[rs][c8+e] = a[e];
  __syncthreads();
  float s = red[0][t];
  #pragma unroll
  for (int r=1;r<8;r++) s += red[r][t];
  psum[blk*256 + t] = s;
}
__global__ __launch_bounds__(256) void k_cm2(const float* __restrict__ psum,
                                             float* __restrict__ m){
  int b = blockIdx.x, c = threadIdx.x;
  float s = 0.f;
  for (int ch=0; ch<64; ch++) s += psum[(b*64+ch)*256 + c];
  m[b*256 + c] = s*(1.f/16384.f);
}

// ---------------- weight transpose to bf16 (Bt layout [N][K])
__global__ __launch_bounds__(256) void k_prep_nt(const float* __restrict__ W,
                                                 unsigned short* __restrict__ WT, int K){
  int idx = blockIdx.x*256 + threadIdx.x;
  int j = idx / K, k = idx - j*K;
  WT[idx] = f2bf(W[(size_t)k*256 + j]);
}

// geo weights -> FP16, layout [10][256 n][256 k]
__global__ __launch_bounds__(256) void k_prep_geoT(const float* __restrict__ wl,
                                                   const float* __restrict__ wg,
                                                   unsigned short* __restrict__ WT){
  int idx = blockIdx.x*256 + threadIdx.x;
  int sg = idx >> 16, rem = idx & 65535;
  int j = rem >> 8, k = rem & 255;
  float v;
  if (sg < 8){
    int si = sg >> 1, s = 1 << si;
    bool neg = sg & 1;
    int krow = neg ? ((k + s) & 255) : k;
    float wi = wl[(size_t)((2*si)*256 + krow)*256 + j];
    float ww = wl[(size_t)((2*si+1)*256 + krow)*256 + j];
    v = neg ? (wi - ww) : (wi + ww);
  } else {
    v = -2.f * wg[(size_t)((sg-8)*2*256 + k)*256 + j];
  }
  WT[idx] = f2h(v);
}

// W_eff (fp16, [b][j=n][c=k])
__global__ __launch_bounds__(256) void k_prep_weff(const float* __restrict__ wg,
                                                   const float* __restrict__ m,
                                                   unsigned short* __restrict__ WT){
  int b = blockIdx.x >> 8, c = blockIdx.x & 255, j = threadIdx.x;
  float acc = 0.f;
  #pragma unroll
  for (int si=0; si<2; ++si){
    int s = si+1;
    int cm = (c - s) & 255, cp = (c + s) & 255;
    float wi_c  = wg[(size_t)((2*si)*256 + c)*256 + j];
    float ww_c  = wg[(size_t)((2*si+1)*256 + c)*256 + j];
    float wi_cp = wg[(size_t)((2*si)*256 + cp)*256 + j];
    float ww_cp = wg[(size_t)((2*si+1)*256 + cp)*256 + j];
    acc += m[b*256+cm]*(wi_c+ww_c) + m[b*256+cp]*(wi_cp-ww_cp);
  }
  WT[(size_t)b*65536 + (size_t)j*256 + c] = f2h(acc);
}

// w_gate rows 0-255 -> bf16 panels [8 k32][4 q][256 n][8 e]
__global__ __launch_bounds__(256) void k_prep_wgx(const float* __restrict__ wg,
                                                  unsigned short* __restrict__ WT){
  int idx = blockIdx.x*256 + threadIdx.x;
  int e = idx&7, n=(idx>>3)&255, q=(idx>>11)&3, k32=idx>>13;
  int k = k32*32 + q*8 + e;
  WT[idx] = f2bf(wg[(size_t)k*256 + n]);
}
// w_gate rows 256-511 -> fp16 panels [8 k32][4 q][256 n][8 e]
__global__ __launch_bounds__(256) void k_prep_wgg(const float* __restrict__ wg,
                                                  unsigned short* __restrict__ WT){
  int idx = blockIdx.x*256 + threadIdx.x;
  int e = idx&7, n=(idx>>3)&255, q=(idx>>11)&3, k32=idx>>13;
  int k = k32*32 + q*8 + e;
  WT[idx] = f2h(wg[(size_t)(256+k)*256 + n]);
}

// ---------------- fused depthwise 3x3 + 3x3 + BN + SiLU - z_det (XN dense)
__global__ __launch_bounds__(256) void k_dwf(const unsigned short* __restrict__ XN,
                                             const float* __restrict__ w1g,
                                             const float* __restrict__ w2g,
                                             const float* __restrict__ bg,
                                             const float* __restrict__ bm_,
                                             const float* __restrict__ bv,
                                             const unsigned short* __restrict__ zdet,
                                             unsigned short* __restrict__ zcx){
  __shared__ unsigned short t0[12800];   // [20][20][32] bf16
  __shared__ unsigned short t1[10368];   // [18][18][32] fp16
  int t = blockIdx.x;
  int img = t >> 6, ty = (t>>3)&7, tx = t&7;
  int c0 = blockIdx.y*32;
  int tid = threadIdx.x;
  int ch = tid & 31;
  int c = c0 + ch;
  for (int v = tid; v < 3200; v += 256){
    int py = v / 160, rem = v - py*160;
    int px = rem >> 3, ch4 = (rem & 7)*4;
    int gpy = ty*16 - 2 + py, gpx = tx*16 - 2 + px;
    ushort4v val = {0,0,0,0};
    if ((unsigned)gpy < 128u && (unsigned)gpx < 128u){
      size_t gp = (size_t)(img*16384 + gpy*128 + gpx);
      val = *(const ushort4v*)&XN[gp*256 + c0 + ch4];
    }
    *(ushort4v*)&t0[(py*20+px)*32 + ch4] = val;
  }
  float w1[9], w2[9];
  #pragma unroll
  for (int k=0;k<9;k++){ w1[k] = w1g[k*256 + c]; w2[k] = w2g[k*256 + c]; }
  __syncthreads();
  for (int p = tid>>5; p < 324; p += 8){
    int py = p / 18, px = p - py*18;
    int gpy = ty*16 - 1 + py, gpx = tx*16 - 1 + px;
    float acc = 0.f;
    #pragma unroll
    for (int dy=0; dy<3; ++dy)
      #pragma unroll
      for (int dx=0; dx<3; ++dx)
        acc += bf2f(t0[((py+dy)*20 + px+dx)*32 + ch]) * w1[dy*3+dx];
    bool valid = ((unsigned)gpy < 128u) && ((unsigned)gpx < 128u);
    t1[p*32 + ch] = valid ? f2h(acc) : (unsigned short)0;
  }
  __syncthreads();
  float bmv = bm_[c];
  float rsbg = rsqrtf(bv[c] + 1e-3f) * bg[c];
  for (int p = tid>>5; p < 256; p += 8){
    int py = p >> 4, px = p & 15;
    float acc = 0.f;
    #pragma unroll
    for (int dy=0; dy<3; ++dy)
      #pragma unroll
      for (int dx=0; dx<3; ++dx)
        acc += h2f(t1[((py+dy)*18 + px+dx)*32 + ch]) * w2[dy*3+dx];
    float tv = (acc - bmv) * rsbg;
    float sv = tv / (1.f + __expf(-tv));
    size_t gp = (size_t)(img*16384 + (ty*16+py)*128 + tx*16+px);
    float z = sv - h2f(zdet[gp*256 + c]);
    zcx[gp*256 + c] = f2h(z);
  }
}

// ---------------- z_det GEMM: ZDET = XN[65536,256] @ WDETT^T, fp16 out
__global__ __launch_bounds__(256) void k_gemm0(const unsigned short* __restrict__ A,
                                               const unsigned short* __restrict__ Bt,
                                               unsigned short* __restrict__ outh){
  __shared__ unsigned short As[128*64];
  __shared__ unsigned short Bss[128*64];
  const int tid=threadIdx.x, lane=tid&63, wid=tid>>6;
  const int bm = blockIdx.x*128, bn = blockIdx.y*128;
  const int wr = wid>>1, wc = wid&1;
  f32x4 acc[4][4] = {};
  const int srow = lane>>3;
  const int skc  = ((lane&7) ^ srow) * 8;
  for (int t=0; t<4; ++t){
    int k0 = t*64;
    #pragma unroll
    for (int i=0;i<4;i++){
      int q = wid*4 + i;
      int row = q*8 + srow;
      gll16(A  + (size_t)(bm+row)*256 + k0 + skc, &As[q*512]);
      gll16(Bt + (size_t)(bn+row)*256 + k0 + skc, &Bss[q*512]);
    }
    __syncthreads();
    #pragma unroll
    for (int kk=0; kk<2; ++kk){
      bf16x8 af[4], bfr[4];
      #pragma unroll
      for (int i=0;i<4;i++){
        int rl = wr*64 + i*16 + (lane&15);
        int kc = (kk*32 + (lane>>4)*8) ^ ((rl&7)*8);
        af[i]  = *(const bf16x8*)&As[rl*64 + kc];
        int cl = wc*64 + i*16 + (lane&15);
        int kcb = (kk*32 + (lane>>4)*8) ^ ((cl&7)*8);
        bfr[i] = *(const bf16x8*)&Bss[cl*64 + kcb];
      }
      #pragma unroll
      for (int i=0;i<4;i++)
        #pragma unroll
        for (int j=0;j<4;j++)
          acc[i][j] = __builtin_amdgcn_mfma_f32_16x16x32_bf16(af[i], bfr[j], acc[i][j], 0,0,0);
    }
    __syncthreads();
  }
  #pragma unroll
  for (int i=0;i<4;i++)
    #pragma unroll
    for (int j=0;j<4;j++)
      #pragma unroll
      for (int r=0;r<4;r++){
        int row = bm + wr*64 + i*16 + (lane>>4)*4 + r;
        int col = bn + wc*64 + j*16 + (lane&15);
        outh[(size_t)row*256 + col] = f2h(acc[i][j][r]);
      }
}

// ---------------- fused geo GEMM (R3 phase-1) + dual gate GEMM + final mix
template<int S>
__device__ __attribute__((always_inline)) ushort8 shsel(ushort8 hi, ushort8 lo){
  ushort8 r;
  if constexpr (S==0) return hi;
  #pragma unroll
  for (int e=0;e<8;e++) r[e] = (e<S) ? lo[8-S+e] : hi[e-S];
  return r;
}

template<int SEG>
__device__ __attribute__((always_inline)) f16x8 gen2(ushort8 zdh, ushort8 zdl,
      ushort8 zch, ushort8 zcl, ushort8 zcu){
  if constexpr (SEG==10) return __builtin_bit_cast(f16x8, zdh);
  ushort8 sel;
  if constexpr      (SEG==0) sel = shsel<1>(zch, zcl);
  else if constexpr (SEG==1) sel = shsel<7>(zcu, zch);
  else if constexpr (SEG==2) sel = shsel<2>(zch, zcl);
  else if constexpr (SEG==3) sel = shsel<6>(zcu, zch);
  else if constexpr (SEG==4) sel = shsel<4>(zch, zcl);
  else if constexpr (SEG==5) sel = shsel<4>(zcu, zch);
  else if constexpr (SEG==6) sel = zcl;
  else if constexpr (SEG==7) sel = zcu;
  else if constexpr (SEG==8) sel = shsel<1>(zdh, zdl);
  else                       sel = shsel<2>(zdh, zdl);
  return __builtin_bit_cast(f16x8, zdh) * __builtin_bit_cast(f16x8, sel);
}

__global__ __launch_bounds__(256) void k_geo(const unsigned short* __restrict__ zd,
                                             const unsigned short* __restrict__ zc,
                                             const unsigned short* __restrict__ WT_all,
                                             const unsigned short* __restrict__ WeffT,
                                             const unsigned short* __restrict__ WGXP,
                                             const unsigned short* __restrict__ WGGP,
                                             const unsigned short* __restrict__ XN,
                                             const float* __restrict__ x,
                                             const float* __restrict__ gls,
                                             float* __restrict__ out){
  __shared__ unsigned short S[32768];        // 64KB: phase1 ring 3x16KB; phase2 XnS+GfS
  const int tid = threadIdx.x, lane = tid&63, wid = tid>>6;
  const int bm = blockIdx.x*64;
  const int img = blockIdx.x >> 8;
  const int wr = wid>>1, wc = wid&1;         // wave: 32 rows x 128 cols
  f32x4 acc0[8] = {}, acc1[8] = {};

  const int s4 = tid & 3;
  int inv[4];
  #pragma unroll
  for (int g=0; g<4; ++g){
    int n = g*64 + (tid>>2);
    int sw = (n + (n>>2)) & 3;
    inv[g] = n*256 + ((s4^sw)<<3);
  }
  int roff[8];
  #pragma unroll
  for (int fj=0; fj<8; ++fj){
    int n = wc*128 + fj*16 + (lane&15);
    int sw = (n + (n>>2)) & 3;
    roff[fj] = n*32 + (((lane>>4) ^ sw) << 3);
  }

  const int m0 = bm + wr*32 + (lane&15);
  const unsigned short* zdr0 = zd + (size_t)m0*256;
  const unsigned short* zdr1 = zdr0 + 16*256;
  const unsigned short* zcr0 = zc + (size_t)m0*256;
  const unsigned short* zcr1 = zcr0 + 16*256;

  ushort8 zdh0,zdl0,zch0,zcl0,zcu0, zdh1,zdl1,zch1,zcl1,zcu1;
  int cur = 0;

#define STAGE(BUF, SP, KK) { \
    const unsigned short* Wb = ((SP)<10) ? (WT_all + (SP)*65536) : (WeffT + (size_t)img*65536); \
    const unsigned short* Wk = Wb + (KK)*32; \
    unsigned short* db = S + (BUF)*8192 + wid*512; \
    gll16(Wk + inv[0], db); \
    gll16(Wk + inv[1], db + 2048); \
    gll16(Wk + inv[2], db + 4096); \
    gll16(Wk + inv[3], db + 6144); \
  }

  STAGE(0, 0, 0);
  STAGE(1, 1, 0);

#define STEP(P) { \
    asm volatile("s_waitcnt vmcnt(4)" ::: "memory"); \
    __builtin_amdgcn_s_barrier(); \
    if constexpr ((P)==0){ \
      int kc = k32*32 + (lane>>4)*8; \
      int kl = (kc-8)&255, ku = (kc+8)&255; \
      zdh0 = *(const ushort8*)(zdr0 + kc); zdl0 = *(const ushort8*)(zdr0 + kl); \
      zch0 = *(const ushort8*)(zcr0 + kc); zcl0 = *(const ushort8*)(zcr0 + kl); \
      zcu0 = *(const ushort8*)(zcr0 + ku); \
      zdh1 = *(const ushort8*)(zdr1 + kc); zdl1 = *(const ushort8*)(zdr1 + kl); \
      zch1 = *(const ushort8*)(zcr1 + kc); zcl1 = *(const ushort8*)(zcr1 + kl); \
      zcu1 = *(const ushort8*)(zcr1 + ku); \
    } \
    __builtin_amdgcn_sched_barrier(0); \
    { constexpr int s2 = ((P)+2 <= 10) ? (P)+2 : (P)+2-11; \
      int k2 = k32 + (((P)+2 > 10) ? 1 : 0); if (k2 > 7) k2 = 7; \
      int nbuf = cur+2; if (nbuf >= 3) nbuf -= 3; \
      STAGE(nbuf, s2, k2); } \
    __builtin_amdgcn_sched_barrier(0); \
    f16x8 af0 = gen2<(P)>(zdh0,zdl0,zch0,zcl0,zcu0); \
    f16x8 af1 = gen2<(P)>(zdh1,zdl1,zch1,zcl1,zcu1); \
    const unsigned short* bp = S + cur*8192; \
    __builtin_amdgcn_s_setprio(1); \
    _Pragma("unroll") \
    for (int fj=0; fj<8; ++fj){ \
      f16x8 bfr = *(const f16x8*)&bp[roff[fj]]; \
      acc0[fj] = __builtin_amdgcn_mfma_f32_16x16x32_f16(af0, bfr, acc0[fj], 0,0,0); \
      acc1[fj] = __builtin_amdgcn_mfma_f32_16x16x32_f16(af1, bfr, acc1[fj], 0,0,0); \
    } \
    __builtin_amdgcn_s_setprio(0); \
    cur = cur+1; if (cur >= 3) cur -= 3; \
  }

  for (int k32=0; k32<8; ++k32){
    STEP(0) STEP(1) STEP(2) STEP(3) STEP(4) STEP(5)
    STEP(6) STEP(7) STEP(8) STEP(9) STEP(10)
  }
#undef STEP
#undef STAGE

  // ---- phase 2: dual gate GEMM (xn@Wgx + gf@Wgg) + final mix
  asm volatile("s_waitcnt vmcnt(0)" ::: "memory");
  __syncthreads();
  unsigned short* XnS = &S[0];       // [64][256] bf16, chunk-swizzled
  unsigned short* GfS = &S[16384];   // [64][256] fp16, col-swizzled

  // store g_feat to GfS
  #pragma unroll
  for (int fj=0; fj<8; ++fj)
    #pragma unroll
    for (int r=0; r<4; ++r){
      int col = wc*128 + fj*16 + (lane&15);
      int rl0 = wr*32 + (lane>>4)*4 + r;
      int rl1 = rl0 + 16;
      GfS[rl0*256 + (col ^ ((rl0&7)<<3))] = f2h(acc0[fj][r]);
      GfS[rl1*256 + (col ^ ((rl1&7)<<3))] = f2h(acc1[fj][r]);
    }
  // stage XnS: linear LDS dest, pre-swizzled global source (rule #21)
  #pragma unroll
  for (int i=0; i<8; ++i){
    int group = wid*8 + i;
    int chunk0 = group*64;                       // + lane implicit
    int row = (chunk0 + lane) >> 5;
    int c3  = (chunk0 + lane) & 31;
    const unsigned short* src = XN + (size_t)(bm + row)*256 + ((c3 ^ (row&7))<<3);
    gll16(src, XnS + chunk0*8);
  }
  {
    f32x4 zz = {};
    #pragma unroll
    for (int fj=0; fj<8; ++fj){ acc0[fj] = zz; acc1[fj] = zz; }
  }
  __syncthreads();

  // gate = XnS @ WGXP (bf16) + GfS @ WGGP (fp16), K=256 each
  const int q = lane>>4;
  const int ra0 = wr*32 + (lane&15);
  const int ra1 = ra0 + 16;
  #pragma unroll
  for (int k32=0; k32<8; ++k32){
    int kc = k32*32 + q*8;
    int chx = (k32*4 + q);
    bf16x8 ax0 = *(const bf16x8*)&XnS[ra0*256 + ((chx ^ (ra0&7))<<3)];
    bf16x8 ax1 = *(const bf16x8*)&XnS[ra1*256 + ((chx ^ (ra1&7))<<3)];
    f16x8 ag0 = *(const f16x8*)&GfS[ra0*256 + (kc ^ ((ra0&7)<<3))];
    f16x8 ag1 = *(const f16x8*)&GfS[ra1*256 + (kc ^ ((ra1&7)<<3))];
    const unsigned short* wpx = WGXP + k32*8192 + q*2048 + (wc*128 + (lane&15))*8;
    const unsigned short* wpg = WGGP + k32*8192 + q*2048 + (wc*128 + (lane&15))*8;
    #pragma unroll
    for (int fj=0; fj<8; ++fj){
      bf16x8 bx = *(const bf16x8*)(wpx + fj*128);
      acc0[fj] = __builtin_amdgcn_mfma_f32_16x16x32_bf16(ax0, bx, acc0[fj], 0,0,0);
      acc1[fj] = __builtin_amdgcn_mfma_f32_16x16x32_bf16(ax1, bx, acc1[fj], 0,0,0);
      f16x8 bg = *(const f16x8*)(wpg + fj*128);
      acc0[fj] = __builtin_amdgcn_mfma_f32_16x16x32_f16(ag0, bg, acc0[fj], 0,0,0);
      acc1[fj] = __builtin_amdgcn_mfma_f32_16x16x32_f16(ag1, bg, acc1[fj], 0,0,0);
    }
  }

  // epilogue: alpha=sigmoid(gate); out = x + (silu(xn) + alpha*gf)*gamma
  #pragma unroll
  for (int fj=0; fj<8; ++fj){
    int col = wc*128 + fj*16 + (lane&15);
    float gm = gls[col];
    #pragma unroll
    for (int r=0; r<4; ++r)
      #pragma unroll
      for (int g2=0; g2<2; ++g2){
        int rl = wr*32 + (lane>>4)*4 + r + g2*16;
        int row = bm + rl;
        float gf = h2f(GfS[rl*256 + (col ^ ((rl&7)<<3))]);
        float xn = bf2f(XnS[rl*256 + (((col>>3) ^ (rl&7))<<3) + (col&7)]);
        float gv = g2 ? acc1[fj][r] : acc0[fj][r];
        float alpha = 1.f/(1.f+__expf(-gv));
        float sl = xn/(1.f+__expf(-xn));
        out[(size_t)row*256 + col] = x[(size_t)row*256 + col] + (sl + alpha*gf)*gm;
      }
  }
}

extern "C" void kernel_launch(void* const* d_in, const int* in_sizes, int n_in,
                              void* d_out, int out_size, void* d_ws, size_t ws_size,
                              hipStream_t stream){
  (void)in_sizes; (void)n_in; (void)out_size; (void)ws_size;
  const float* x    = (const float*)d_in[0];
  const float* lng  = (const float*)d_in[1];
  const float* wdet = (const float*)d_in[2];
  const float* dw1  = (const float*)d_in[3];
  const float* dw2  = (const float*)d_in[4];
  const float* bng  = (const float*)d_in[5];
  const float* bnm  = (const float*)d_in[6];
  const float* bnv  = (const float*)d_in[7];
  const float* wloc = (const float*)d_in[8];
  const float* wglo = (const float*)d_in[9];
  const float* wgat = (const float*)d_in[10];
  const float* gls  = (const float*)d_in[11];
  float* out = (float*)d_out;
  char* ws = (char*)d_ws;

  unsigned short* XN    = (unsigned short*)(ws);                  // 32 MB [65536][256] bf16
  unsigned short* ZDET  = (unsigned short*)(ws + 33554432);       // 32 MB fp16
  unsigned short* ZCX   = (unsigned short*)(ws + 67108864);       // 32 MB fp16
  unsigned short* WTALL = (unsigned short*)(ws + 100663296);      // 1.25 MB fp16 [10][n][k]
  unsigned short* WEFFT = (unsigned short*)(ws + 101974016);      // 512 KB fp16 [b][n][k]
  unsigned short* WDETT = (unsigned short*)(ws + 102498304);      // 128 KB bf16
  unsigned short* WGXP  = (unsigned short*)(ws + 102629376);      // 128 KB bf16 panels
  unsigned short* WGGP  = (unsigned short*)(ws + 102760448);      // 128 KB fp16 panels
  float* PSUM  = (float*)(ws + 102891520);                        // 256 KB
  float* MMEAN = (float*)(ws + 103153664);                        // 4 KB

  k_ln<<<16384, 256, 0, stream>>>(x, lng, XN);
  k_cm1<<<256, 256, 0, stream>>>(XN, PSUM);
  k_cm2<<<4, 256, 0, stream>>>(PSUM, MMEAN);
  k_prep_nt<<<256, 256, 0, stream>>>(wdet, WDETT, 256);
  k_prep_wgx<<<256, 256, 0, stream>>>(wgat, WGXP);
  k_prep_wgg<<<256, 256, 0, stream>>>(wgat, WGGP);
  k_prep_geoT<<<2560, 256, 0, stream>>>(wloc, wglo, WTALL);
  k_prep_weff<<<1024, 256, 0, stream>>>(wglo, MMEAN, WEFFT);
  k_gemm0<<<dim3(512,2), 256, 0, stream>>>(XN, WDETT, ZDET);
  k_dwf<<<dim3(256,8), 256, 0, stream>>>(XN, dw1, dw2, bng, bnm, bnv, ZDET, ZCX);
  k_geo<<<1024, 256, 0, stream>>>(ZDET, ZCX, WTALL, WEFFT, WGXP, WGGP, XN, x, gls, out);
}

// Round 13
// 335.477 us; speedup vs baseline: 1.2066x; 1.2066x over previous
//
#include <hip/hip_runtime.h>

typedef __attribute__((ext_vector_type(8))) short bf16x8;
typedef __attribute__((ext_vector_type(8))) unsigned short ushort8;
typedef __attribute__((ext_vector_type(4))) unsigned short ushort4v;
typedef __attribute__((ext_vector_type(4))) float f32x4;
typedef __attribute__((ext_vector_type(4))) float float4v;
typedef __attribute__((ext_vector_type(8))) _Float16 f16x8;

__device__ inline unsigned short f2bf(float f){
  unsigned u = __builtin_bit_cast(unsigned, f);
  return (unsigned short)((u + 0x7fffu + ((u>>16)&1u)) >> 16);
}
__device__ inline float bf2f(unsigned short h){
  return __builtin_bit_cast(float, (unsigned)h << 16);
}
__device__ inline unsigned short f2h(float f){
  return __builtin_bit_cast(unsigned short, (_Float16)f);
}
__device__ inline float h2f(unsigned short u){
  return (float)__builtin_bit_cast(_Float16, u);
}

__device__ inline void gll16(const void* g, void* l){
  __builtin_amdgcn_global_load_lds((const __attribute__((address_space(1))) void*)g,
                                   (__attribute__((address_space(3))) void*)l, 16, 0, 0);
}

// ---------------- LayerNorm: one wave per row -> XN [65536][256] bf16 (dense)
__global__ __launch_bounds__(256) void k_ln(const float* __restrict__ x,
                                            const float* __restrict__ g,
                                            unsigned short* __restrict__ XN){
  int wid = threadIdx.x >> 6, lane = threadIdx.x & 63;
  int row = blockIdx.x*4 + wid;
  float4v v = *(const float4v*)&x[(size_t)row*256 + lane*4];
  float4v gv = *(const float4v*)&g[lane*4];
  float s  = v[0]+v[1]+v[2]+v[3];
  float s2 = v[0]*v[0]+v[1]*v[1]+v[2]*v[2]+v[3]*v[3];
  #pragma unroll
  for (int m=32; m>=1; m>>=1){ s += __shfl_xor(s, m, 64); s2 += __shfl_xor(s2, m, 64); }
  float mu  = s*(1.f/256.f);
  float var = s2*(1.f/256.f) - mu*mu;
  float rst = rsqrtf(var + 1e-6f);
  ushort4v o;
  #pragma unroll
  for (int e=0;e<4;e++) o[e] = f2bf((v[e]-mu)*rst*gv[e]);
  *(ushort4v*)&XN[(size_t)row*256 + lane*4] = o;
}

// ---------------- column partial sums (dense XN), coalesced
__global__ __launch_bounds__(256) void k_cm1(const unsigned short* __restrict__ XN,
                                             float* __restrict__ psum){
  __shared__ float red[8][256];
  int blk = blockIdx.x, t = threadIdx.x;
  int rs = t >> 5, c8 = (t & 31)*8;
  float a[8] = {0,0,0,0,0,0,0,0};
  #pragma unroll
  for (int i=0; i<8; ++i){
    int row = blk*64 + rs + i*8;
    ushort8 v = *(const ushort8*)&XN[(size_t)row*256 + c8];
    #pragma unroll
    for (int e=0;e<8;e++) a[e] += bf2f(v[e]);
  }
  #pragma unroll
  for (int e=0;e<8;e++) red[rs][c8+e] = a[e];
  __syncthreads();
  float s = red[0][t];
  #pragma unroll
  for (int r=1;r<8;r++) s += red[r][t];
  psum[blk*256 + t] = s;
}
__global__ __launch_bounds__(256) void k_cm2(const float* __restrict__ psum,
                                             float* __restrict__ m){
  int b = blockIdx.x, c = threadIdx.x;
  float s = 0.f;
  for (int ch=0; ch<64; ch++) s += psum[(b*64+ch)*256 + c];
  m[b*256 + c] = s*(1.f/16384.f);
}

// ---------------- weight transpose to bf16 (Bt layout [N][K])
__global__ __launch_bounds__(256) void k_prep_nt(const float* __restrict__ W,
                                                 unsigned short* __restrict__ WT, int K){
  int idx = blockIdx.x*256 + threadIdx.x;
  int j = idx / K, k = idx - j*K;
  WT[idx] = f2bf(W[(size_t)k*256 + j]);
}

// geo weights -> FP16, layout [10][256 n][256 k]
__global__ __launch_bounds__(256) void k_prep_geoT(const float* __restrict__ wl,
                                                   const float* __restrict__ wg,
                                                   unsigned short* __restrict__ WT){
  int idx = blockIdx.x*256 + threadIdx.x;
  int sg = idx >> 16, rem = idx & 65535;
  int j = rem >> 8, k = rem & 255;
  float v;
  if (sg < 8){
    int si = sg >> 1, s = 1 << si;
    bool neg = sg & 1;
    int krow = neg ? ((k + s) & 255) : k;
    float wi = wl[(size_t)((2*si)*256 + krow)*256 + j];
    float ww = wl[(size_t)((2*si+1)*256 + krow)*256 + j];
    v = neg ? (wi - ww) : (wi + ww);
  } else {
    v = -2.f * wg[(size_t)((sg-8)*2*256 + k)*256 + j];
  }
  WT[idx] = f2h(v);
}

// W_eff (fp16, [b][j=n][c=k])
__global__ __launch_bounds__(256) void k_prep_weff(const float* __restrict__ wg,
                                                   const float* __restrict__ m,
                                                   unsigned short* __restrict__ WT){
  int b = blockIdx.x >> 8, c = blockIdx.x & 255, j = threadIdx.x;
  float acc = 0.f;
  #pragma unroll
  for (int si=0; si<2; ++si){
    int s = si+1;
    int cm = (c - s) & 255, cp = (c + s) & 255;
    float wi_c  = wg[(size_t)((2*si)*256 + c)*256 + j];
    float ww_c  = wg[(size_t)((2*si+1)*256 + c)*256 + j];
    float wi_cp = wg[(size_t)((2*si)*256 + cp)*256 + j];
    float ww_cp = wg[(size_t)((2*si+1)*256 + cp)*256 + j];
    acc += m[b*256+cm]*(wi_c+ww_c) + m[b*256+cp]*(wi_cp-ww_cp);
  }
  WT[(size_t)b*65536 + (size_t)j*256 + c] = f2h(acc);
}

// w_gate rows 256-511 (g_feat part) -> fp16 panels [8 k32][4 q][256 n][8 e]
__global__ __launch_bounds__(256) void k_prep_wgg(const float* __restrict__ wg,
                                                  unsigned short* __restrict__ WT){
  int idx = blockIdx.x*256 + threadIdx.x;     // 65536
  int e = idx&7, n=(idx>>3)&255, q=(idx>>11)&3, k32=idx>>13;
  int k = k32*32 + q*8 + e;
  WT[idx] = f2h(wg[(size_t)(256+k)*256 + n]);
}

// ---------------- fused depthwise 3x3 + 3x3 + BN + SiLU - z_det (XN dense)
__global__ __launch_bounds__(256) void k_dwf(const unsigned short* __restrict__ XN,
                                             const float* __restrict__ w1g,
                                             const float* __restrict__ w2g,
                                             const float* __restrict__ bg,
                                             const float* __restrict__ bm_,
                                             const float* __restrict__ bv,
                                             const unsigned short* __restrict__ zdet,
                                             unsigned short* __restrict__ zcx){
  __shared__ unsigned short t0[12800];   // [20][20][32] bf16
  __shared__ unsigned short t1[10368];   // [18][18][32] fp16
  int t = blockIdx.x;
  int img = t >> 6, ty = (t>>3)&7, tx = t&7;
  int c0 = blockIdx.y*32;
  int tid = threadIdx.x;
  int ch = tid & 31;
  int c = c0 + ch;
  for (int v = tid; v < 3200; v += 256){
    int py = v / 160, rem = v - py*160;
    int px = rem >> 3, ch4 = (rem & 7)*4;
    int gpy = ty*16 - 2 + py, gpx = tx*16 - 2 + px;
    ushort4v val = {0,0,0,0};
    if ((unsigned)gpy < 128u && (unsigned)gpx < 128u){
      size_t gp = (size_t)(img*16384 + gpy*128 + gpx);
      val = *(const ushort4v*)&XN[gp*256 + c0 + ch4];
    }
    *(ushort4v*)&t0[(py*20+px)*32 + ch4] = val;
  }
  float w1[9], w2[9];
  #pragma unroll
  for (int k=0;k<9;k++){ w1[k] = w1g[k*256 + c]; w2[k] = w2g[k*256 + c]; }
  __syncthreads();
  for (int p = tid>>5; p < 324; p += 8){
    int py = p / 18, px = p - py*18;
    int gpy = ty*16 - 1 + py, gpx = tx*16 - 1 + px;
    float acc = 0.f;
    #pragma unroll
    for (int dy=0; dy<3; ++dy)
      #pragma unroll
      for (int dx=0; dx<3; ++dx)
        acc += bf2f(t0[((py+dy)*20 + px+dx)*32 + ch]) * w1[dy*3+dx];
    bool valid = ((unsigned)gpy < 128u) && ((unsigned)gpx < 128u);
    t1[p*32 + ch] = valid ? f2h(acc) : (unsigned short)0;
  }
  __syncthreads();
  float bmv = bm_[c];
  float rsbg = rsqrtf(bv[c] + 1e-3f) * bg[c];
  for (int p = tid>>5; p < 256; p += 8){
    int py = p >> 4, px = p & 15;
    float acc = 0.f;
    #pragma unroll
    for (int dy=0; dy<3; ++dy)
      #pragma unroll
      for (int dx=0; dx<3; ++dx)
        acc += h2f(t1[((py+dy)*18 + px+dx)*32 + ch]) * w2[dy*3+dx];
    float tv = (acc - bmv) * rsbg;
    float sv = tv / (1.f + __expf(-tv));
    size_t gp = (size_t)(img*16384 + (ty*16+py)*128 + tx*16+px);
    float z = sv - h2f(zdet[gp*256 + c]);
    zcx[gp*256 + c] = f2h(z);
  }
}

// ---------------- dual-output MFMA GEMM: z_det and gate_x, K=256, A dense
// grid (4, 512): x = n-block (0,1 -> z_det cols; 2,3 -> gate_x cols), y = m-block
__global__ __launch_bounds__(256) void k_gemmD(const unsigned short* __restrict__ A,
                                               const unsigned short* __restrict__ Bt1,
                                               const unsigned short* __restrict__ Bt2,
                                               unsigned short* __restrict__ o1,
                                               unsigned short* __restrict__ o2){
  __shared__ unsigned short As[128*64];
  __shared__ unsigned short Bss[128*64];
  const int tid=threadIdx.x, lane=tid&63, wid=tid>>6;
  const int nb = blockIdx.x;
  const int bm = blockIdx.y*128;
  const unsigned short* Bt = (nb<2)? Bt1 : Bt2;
  unsigned short* outh = (nb<2)? o1 : o2;
  const int bn = (nb&1)*128;
  const int wr = wid>>1, wc = wid&1;
  f32x4 acc[4][4] = {};
  const int srow = lane>>3;
  const int skc  = ((lane&7) ^ srow) * 8;
  for (int t=0; t<4; ++t){
    int k0 = t*64;
    #pragma unroll
    for (int i=0;i<4;i++){
      int q = wid*4 + i;
      int row = q*8 + srow;
      gll16(A  + (size_t)(bm+row)*256 + k0 + skc, &As[q*512]);
      gll16(Bt + (size_t)(bn+row)*256 + k0 + skc, &Bss[q*512]);
    }
    __syncthreads();
    #pragma unroll
    for (int kk=0; kk<2; ++kk){
      bf16x8 af[4], bfr[4];
      #pragma unroll
      for (int i=0;i<4;i++){
        int rl = wr*64 + i*16 + (lane&15);
        int kc = (kk*32 + (lane>>4)*8) ^ ((rl&7)*8);
        af[i]  = *(const bf16x8*)&As[rl*64 + kc];
        int cl = wc*64 + i*16 + (lane&15);
        int kcb = (kk*32 + (lane>>4)*8) ^ ((cl&7)*8);
        bfr[i] = *(const bf16x8*)&Bss[cl*64 + kcb];
      }
      #pragma unroll
      for (int i=0;i<4;i++)
        #pragma unroll
        for (int j=0;j<4;j++)
          acc[i][j] = __builtin_amdgcn_mfma_f32_16x16x32_bf16(af[i], bfr[j], acc[i][j], 0,0,0);
    }
    __syncthreads();
  }
  #pragma unroll
  for (int i=0;i<4;i++)
    #pragma unroll
    for (int j=0;j<4;j++)
      #pragma unroll
      for (int r=0;r<4;r++){
        int row = bm + wr*64 + i*16 + (lane>>4)*4 + r;
        int col = bn + wc*64 + j*16 + (lane&15);
        outh[(size_t)row*256 + col] = f2h(acc[i][j][r]);
      }
}

// ---------------- fused geo GEMM (R3 phase-1) + gate GEMM + final mix (R11)
template<int S>
__device__ __attribute__((always_inline)) ushort8 shsel(ushort8 hi, ushort8 lo){
  ushort8 r;
  if constexpr (S==0) return hi;
  #pragma unroll
  for (int e=0;e<8;e++) r[e] = (e<S) ? lo[8-S+e] : hi[e-S];
  return r;
}

template<int SEG>
__device__ __attribute__((always_inline)) f16x8 gen2(ushort8 zdh, ushort8 zdl,
      ushort8 zch, ushort8 zcl, ushort8 zcu){
  if constexpr (SEG==10) return __builtin_bit_cast(f16x8, zdh);
  ushort8 sel;
  if constexpr      (SEG==0) sel = shsel<1>(zch, zcl);
  else if constexpr (SEG==1) sel = shsel<7>(zcu, zch);
  else if constexpr (SEG==2) sel = shsel<2>(zch, zcl);
  else if constexpr (SEG==3) sel = shsel<6>(zcu, zch);
  else if constexpr (SEG==4) sel = shsel<4>(zch, zcl);
  else if constexpr (SEG==5) sel = shsel<4>(zcu, zch);
  else if constexpr (SEG==6) sel = zcl;
  else if constexpr (SEG==7) sel = zcu;
  else if constexpr (SEG==8) sel = shsel<1>(zdh, zdl);
  else                       sel = shsel<2>(zdh, zdl);
  return __builtin_bit_cast(f16x8, zdh) * __builtin_bit_cast(f16x8, sel);
}

__global__ __launch_bounds__(256) void k_geo(const unsigned short* __restrict__ zd,
                                             const unsigned short* __restrict__ zc,
                                             const unsigned short* __restrict__ WT_all,
                                             const unsigned short* __restrict__ WeffT,
                                             const unsigned short* __restrict__ WGGP,
                                             const unsigned short* __restrict__ GXB,
                                             const unsigned short* __restrict__ XN,
                                             const float* __restrict__ x,
                                             const float* __restrict__ gls,
                                             float* __restrict__ out){
  __shared__ unsigned short Bs[3][8192];     // ring-3 panels; reused as Gs in phase 2
  const int tid = threadIdx.x, lane = tid&63, wid = tid>>6;
  const int bm = blockIdx.x*64;
  const int img = blockIdx.x >> 8;
  const int wr = wid>>1, wc = wid&1;         // wave: 32 rows x 128 cols
  f32x4 acc0[8] = {}, acc1[8] = {};

  const int s4 = tid & 3;
  int inv[4];
  #pragma unroll
  for (int g=0; g<4; ++g){
    int n = g*64 + (tid>>2);
    int sw = (n + (n>>2)) & 3;
    inv[g] = n*256 + ((s4^sw)<<3);
  }
  int roff[8];
  #pragma unroll
  for (int fj=0; fj<8; ++fj){
    int n = wc*128 + fj*16 + (lane&15);
    int sw = (n + (n>>2)) & 3;
    roff[fj] = n*32 + (((lane>>4) ^ sw) << 3);
  }

  const int m0 = bm + wr*32 + (lane&15);
  const unsigned short* zdr0 = zd + (size_t)m0*256;
  const unsigned short* zdr1 = zdr0 + 16*256;
  const unsigned short* zcr0 = zc + (size_t)m0*256;
  const unsigned short* zcr1 = zcr0 + 16*256;

  ushort8 zdh0,zdl0,zch0,zcl0,zcu0, zdh1,zdl1,zch1,zcl1,zcu1;
  int cur = 0;

#define STAGE(BUF, SP, KK) { \
    const unsigned short* Wb = ((SP)<10) ? (WT_all + (SP)*65536) : (WeffT + (size_t)img*65536); \
    const unsigned short* Wk = Wb + (KK)*32; \
    gll16(Wk + inv[0], &Bs[BUF][0*2048 + wid*512]); \
    gll16(Wk + inv[1], &Bs[BUF][1*2048 + wid*512]); \
    gll16(Wk + inv[2], &Bs[BUF][2*2048 + wid*512]); \
    gll16(Wk + inv[3], &Bs[BUF][3*2048 + wid*512]); \
  }

  STAGE(0, 0, 0);
  STAGE(1, 1, 0);

#define STEP(P) { \
    asm volatile("s_waitcnt vmcnt(4)" ::: "memory"); \
    __builtin_amdgcn_s_barrier(); \
    if constexpr ((P)==0){ \
      int kc = k32*32 + (lane>>4)*8; \
      int kl = (kc-8)&255, ku = (kc+8)&255; \
      zdh0 = *(const ushort8*)(zdr0 + kc); zdl0 = *(const ushort8*)(zdr0 + kl); \
      zch0 = *(const ushort8*)(zcr0 + kc); zcl0 = *(const ushort8*)(zcr0 + kl); \
      zcu0 = *(const ushort8*)(zcr0 + ku); \
      zdh1 = *(const ushort8*)(zdr1 + kc); zdl1 = *(const ushort8*)(zdr1 + kl); \
      zch1 = *(const ushort8*)(zcr1 + kc); zcl1 = *(const ushort8*)(zcr1 + kl); \
      zcu1 = *(const ushort8*)(zcr1 + ku); \
    } \
    __builtin_amdgcn_sched_barrier(0); \
    { constexpr int s2 = ((P)+2 <= 10) ? (P)+2 : (P)+2-11; \
      int k2 = k32 + (((P)+2 > 10) ? 1 : 0); if (k2 > 7) k2 = 7; \
      int nbuf = cur+2; if (nbuf >= 3) nbuf -= 3; \
      STAGE(nbuf, s2, k2); } \
    __builtin_amdgcn_sched_barrier(0); \
    f16x8 af0 = gen2<(P)>(zdh0,zdl0,zch0,zcl0,zcu0); \
    f16x8 af1 = gen2<(P)>(zdh1,zdl1,zch1,zcl1,zcu1); \
    const unsigned short* bp = &Bs[cur][0]; \
    __builtin_amdgcn_s_setprio(1); \
    _Pragma("unroll") \
    for (int fj=0; fj<8; ++fj){ \
      f16x8 bfr = *(const f16x8*)&bp[roff[fj]]; \
      acc0[fj] = __builtin_amdgcn_mfma_f32_16x16x32_f16(af0, bfr, acc0[fj], 0,0,0); \
      acc1[fj] = __builtin_amdgcn_mfma_f32_16x16x32_f16(af1, bfr, acc1[fj], 0,0,0); \
    } \
    __builtin_amdgcn_s_setprio(0); \
    cur = cur+1; if (cur >= 3) cur -= 3; \
  }

  for (int k32=0; k32<8; ++k32){
    STEP(0) STEP(1) STEP(2) STEP(3) STEP(4) STEP(5)
    STEP(6) STEP(7) STEP(8) STEP(9) STEP(10)
  }
#undef STEP
#undef STAGE

  // ---- phase 2: gate GEMM + final mix. Reuse Bs memory as Gs[64][256] fp16.
  asm volatile("s_waitcnt vmcnt(0)" ::: "memory");
  __syncthreads();                             // all panel stages landed, all reads done
  unsigned short* Gs = &Bs[0][0];

  #pragma unroll
  for (int fj=0; fj<8; ++fj)
    #pragma unroll
    for (int r=0; r<4; ++r){
      int col = wc*128 + fj*16 + (lane&15);
      int rl0 = wr*32 + (lane>>4)*4 + r;
      int rl1 = rl0 + 16;
      Gs[rl0*256 + (col ^ ((rl0&7)<<3))] = f2h(acc0[fj][r]);
      Gs[rl1*256 + (col ^ ((rl1&7)<<3))] = f2h(acc1[fj][r]);
    }
  {
    f32x4 zz = {};
    #pragma unroll
    for (int fj=0; fj<8; ++fj){ acc0[fj] = zz; acc1[fj] = zz; }
  }
  __syncthreads();

  // gate-g GEMM: acc = Gs[64 rows][256 K] @ WGGP (K=256), fragments from L2
  const int q = lane>>4;
  #pragma unroll
  for (int k32=0; k32<8; ++k32){
    int kc = k32*32 + q*8;
    int ra0 = wr*32 + (lane&15);
    int ra1 = ra0 + 16;
    f16x8 af0 = *(const f16x8*)&Gs[ra0*256 + (kc ^ ((ra0&7)<<3))];
    f16x8 af1 = *(const f16x8*)&Gs[ra1*256 + (kc ^ ((ra1&7)<<3))];
    const unsigned short* wp = WGGP + k32*8192 + q*2048 + (wc*128 + (lane&15))*8;
    #pragma unroll
    for (int fj=0; fj<8; ++fj){
      f16x8 bfr = *(const f16x8*)(wp + fj*128);
      acc0[fj] = __builtin_amdgcn_mfma_f32_16x16x32_f16(af0, bfr, acc0[fj], 0,0,0);
      acc1[fj] = __builtin_amdgcn_mfma_f32_16x16x32_f16(af1, bfr, acc1[fj], 0,0,0);
    }
  }

  // epilogue: alpha = sigmoid(gate_x + gate_g); out = x + (silu(xn) + alpha*gf)*gamma
  #pragma unroll
  for (int fj=0; fj<8; ++fj)
    #pragma unroll
    for (int r=0; r<4; ++r){
      int col = wc*128 + fj*16 + (lane&15);
      float gm = gls[col];
      #pragma unroll
      for (int g2=0; g2<2; ++g2){
        int rl = wr*32 + (lane>>4)*4 + r + g2*16;
        int row = bm + rl;
        float gf = h2f(Gs[rl*256 + (col ^ ((rl&7)<<3))]);
        float gv = (g2 ? acc1[fj][r] : acc0[fj][r]) + h2f(GXB[(size_t)row*256 + col]);
        float alpha = 1.f/(1.f+__expf(-gv));
        float xn = bf2f(XN[(size_t)row*256 + col]);
        float sl = xn/(1.f+__expf(-xn));
        out[(size_t)row*256 + col] = x[(size_t)row*256 + col] + (sl + alpha*gf)*gm;
      }
    }
}

extern "C" void kernel_launch(void* const* d_in, const int* in_sizes, int n_in,
                              void* d_out, int out_size, void* d_ws, size_t ws_size,
                              hipStream_t stream){
  (void)in_sizes; (void)n_in; (void)out_size; (void)ws_size;
  const float* x    = (const float*)d_in[0];
  const float* lng  = (const float*)d_in[1];
  const float* wdet = (const float*)d_in[2];
  const float* dw1  = (const float*)d_in[3];
  const float* dw2  = (const float*)d_in[4];
  const float* bng  = (const float*)d_in[5];
  const float* bnm  = (const float*)d_in[6];
  const float* bnv  = (const float*)d_in[7];
  const float* wloc = (const float*)d_in[8];
  const float* wglo = (const float*)d_in[9];
  const float* wgat = (const float*)d_in[10];
  const float* gls  = (const float*)d_in[11];
  float* out = (float*)d_out;
  char* ws = (char*)d_ws;

  unsigned short* XN    = (unsigned short*)(ws);                  // 32 MB [65536][256] bf16
  unsigned short* ZDET  = (unsigned short*)(ws + 33554432);       // 32 MB fp16
  unsigned short* GXB   = (unsigned short*)(ws + 67108864);       // 32 MB fp16 gate_x
  unsigned short* ZCX   = (unsigned short*)(ws + 100663296);      // 32 MB fp16
  unsigned short* WTALL = (unsigned short*)(ws + 134217728);      // 1.25 MB fp16 [10][n][k]
  unsigned short* WEFFT = (unsigned short*)(ws + 135528448);      // 512 KB fp16 [b][n][k]
  unsigned short* WDETT = (unsigned short*)(ws + 136052736);      // 128 KB bf16
  unsigned short* WGXT  = (unsigned short*)(ws + 136183808);      // 128 KB bf16
  unsigned short* WGGP  = (unsigned short*)(ws + 136314880);      // 128 KB fp16 panels
  float* PSUM  = (float*)(ws + 136445952);                        // 256 KB
  float* MMEAN = (float*)(ws + 136708096);                        // 4 KB

  k_ln<<<16384, 256, 0, stream>>>(x, lng, XN);
  k_cm1<<<256, 256, 0, stream>>>(XN, PSUM);
  k_cm2<<<4, 256, 0, stream>>>(PSUM, MMEAN);
  k_prep_nt<<<256, 256, 0, stream>>>(wdet, WDETT, 256);
  k_prep_nt<<<256, 256, 0, stream>>>(wgat, WGXT, 256);
  k_prep_wgg<<<256, 256, 0, stream>>>(wgat, WGGP);
  k_prep_geoT<<<2560, 256, 0, stream>>>(wloc, wglo, WTALL);
  k_prep_weff<<<1024, 256, 0, stream>>>(wglo, MMEAN, WEFFT);
  k_gemmD<<<dim3(4,512), 256, 0, stream>>>(XN, WDETT, WGXT, ZDET, GXB);
  k_dwf<<<dim3(256,8), 256, 0, stream>>>(XN, dw1, dw2, bng, bnm, bnv, ZDET, ZCX);
  k_geo<<<1024, 256, 0, stream>>>(ZDET, ZCX, WTALL, WEFFT, WGGP, GXB, XN, x, gls, out);
}